// Round 11
// baseline (31.713 us; speedup 1.0000x reference)
//
#include <hip/hip_runtime.h>
#include <cstdint>

#define T_STEPS 16
#define V_VECS  1024
#define D_DIM   128
#define B_BATCH 2048
#define BCAP    2048          // per-t list capacity (bulletproof: n <= B)

// ---------------------------------------------------------------------------
// k_score: grid (16 vtiles, 16 t, 4 z), block 256 = 16(tv) x 16(tb).
// Tile 64v x 64b, 4x4 thread tile, A AND X staged in LDS (r10 showed
// X-from-global regresses: gather-VMEM latency > occupancy gain).
// z=4 with chunk stride 256 => every active block runs EXACTLY ONE chunk
// (r7's z=2/stride-128 made half the t's run 2 serial chunks - straggler
// tail). LDS ~69 KB -> 2 blocks/CU = 8 waves/CU.
//
// Phase 0: barrier-light bucketing - 8 ballots issued with no intervening
//          barriers, one barrier, uniform prefix from wcnt[8][4], scatter.
//          Deterministic => all blocks of t derive the IDENTICAL blist.
// Phase 1: stage A^T k-major + fused inverse norms (npart reduce).
// Phase 2: single chunk (cs = z*64): stage X^T k-major, 4x4 register GEMM
//          (identical FMA order to r7 => bit-identical scores), invnorm
//          scale, per-thread argmax over 4 v, shfl_xor {8,4,2,1} across tv
//          lanes (tie -> lowest v, matches jnp.argmax), plain store of
//          packed (ordered_score:32 | (1023-v):16 | b:16) to
//          partial[vt][t][bi]. Cross-block visibility via the KERNEL
//          BOUNDARY only (intra-kernel protocols failed rounds 4-6).
// ---------------------------------------------------------------------------
__global__ __launch_bounds__(256) void k_score(const float* __restrict__ X,
                                               const float* __restrict__ L,
                                               const int* __restrict__ idx,
                                               unsigned long long* __restrict__ partial,
                                               int* __restrict__ counts) {
    __shared__ __align__(16) float As[D_DIM][64];   // 32 KB
    __shared__ __align__(16) float Xs[D_DIM][64];   // 32 KB
    __shared__ float npart[4][64];                  // 1 KB
    __shared__ float invn_s[64];
    __shared__ unsigned short blist[BCAP];          // 4 KB
    __shared__ int wcnt[8][4];

    const int t    = blockIdx.y;
    const int vt   = blockIdx.x;
    const int v0   = vt * 64;
    const int z    = blockIdx.z;
    const int tid  = threadIdx.x;
    const int lane = tid & 63;
    const int w    = tid >> 6;

    // ---- phase 0: barrier-light bucketing ----
    bool mm[8]; int wpre[8];
    #pragma unroll
    for (int r = 0; r < 8; ++r) {
        const bool m = (idx[r * 256 + tid] == t);
        const unsigned long long bal = __ballot(m);
        mm[r]   = m;
        wpre[r] = __popcll(bal & ((1ull << lane) - 1ull));
        if (lane == 0) wcnt[r][w] = __popcll(bal);
    }
    __syncthreads();
    int run = 0;
    #pragma unroll
    for (int r = 0; r < 8; ++r) {
        int base = run;
        #pragma unroll
        for (int w2 = 0; w2 < 4; ++w2) {
            const int c = wcnt[r][w2];      // LDS broadcast (uniform)
            if (w2 < w) base += c;
            run += c;
        }
        if (mm[r]) blist[base + wpre[r]] = (unsigned short)(r * 256 + tid);
    }
    const int n = run;
    if (vt == 0 && z == 0 && tid == 0) counts[t] = n;   // before early return
    const int cs = z * 64;
    if (cs >= n) return;                 // uniform across blocks of t

    // ---- phase 1: stage A^T (k-major) + fused inverse norms ----
    const float4* LA = (const float4*)(L + (size_t)(t * V_VECS + v0) * D_DIM);
    float ss = 0.f;
    #pragma unroll
    for (int p = 0; p < 8; ++p) {
        const int k4 = w + 4 * p;              // 0..31
        const float4 g = LA[lane * 32 + k4];
        As[4 * k4 + 0][lane] = g.x;
        As[4 * k4 + 1][lane] = g.y;
        As[4 * k4 + 2][lane] = g.z;
        As[4 * k4 + 3][lane] = g.w;
        ss += g.x * g.x + g.y * g.y + g.z * g.z + g.w * g.w;
    }
    npart[w][lane] = ss;

    // ---- stage X^T for this block's single chunk ----
    const int brow = cs + lane;
    const int bg = (brow < n) ? (int)blist[brow] : -1;
    const float4* XA = (const float4*)X;
    const float4* xr = XA + (size_t)(bg < 0 ? 0 : bg) * 32;
    #pragma unroll
    for (int p = 0; p < 8; ++p) {
        const int k4 = w + 4 * p;
        float4 g = make_float4(0.f, 0.f, 0.f, 0.f);
        if (bg >= 0) g = xr[k4];
        Xs[4 * k4 + 0][lane] = g.x;
        Xs[4 * k4 + 1][lane] = g.y;
        Xs[4 * k4 + 2][lane] = g.z;
        Xs[4 * k4 + 3][lane] = g.w;
    }
    __syncthreads();
    if (tid < 64) {
        const float s = npart[0][tid] + npart[1][tid] + npart[2][tid] + npart[3][tid];
        invn_s[tid] = rsqrtf(fmaxf(s, 1e-12f));
    }
    __syncthreads();

    const int tv = tid & 15;     // v-group: v = v0 + tv*4 + i
    const int tb = tid >> 4;     // b-group: b-slot = cs + tb*4 + j

    float acc[4][4] = {};
    #pragma unroll 16
    for (int k = 0; k < D_DIM; ++k) {
        const float4 av = *(const float4*)&As[k][tv * 4];
        const float4 xb = *(const float4*)&Xs[k][tb * 4];
        const float a[4] = {av.x, av.y, av.z, av.w};
        const float x[4] = {xb.x, xb.y, xb.z, xb.w};
        #pragma unroll
        for (int i = 0; i < 4; ++i)
            #pragma unroll
            for (int j = 0; j < 4; ++j)
                acc[i][j] += a[i] * x[j];
    }

    // ---- epilogue: argmax over v per b ----
    const float4 inv4 = *(const float4*)&invn_s[tv * 4];
    const float invp[4] = {inv4.x, inv4.y, inv4.z, inv4.w};

    #pragma unroll
    for (int j = 0; j < 4; ++j) {
        float s = acc[0][j] * invp[0];
        int   c = v0 + tv * 4;
        #pragma unroll
        for (int i = 1; i < 4; ++i) {
            const float si = acc[i][j] * invp[i];
            const int   ci = v0 + tv * 4 + i;
            if (si > s) { s = si; c = ci; }          // strict: lowest v wins tie
        }
        #pragma unroll
        for (int m = 8; m >= 1; m >>= 1) {           // reduce across tv lanes
            const float u  = __shfl_xor(s, m);
            const int   cu = __shfl_xor(c, m);
            if (u > s || (u == s && cu < c)) { s = u; c = cu; }
        }
        if (tv == 0) {
            const int bi = cs + tb * 4 + j;
            if (bi < n) {
                unsigned int ub = __float_as_uint(s);
                ub = (ub & 0x80000000u) ? ~ub : (ub | 0x80000000u);
                const unsigned long long key =
                    ((unsigned long long)ub << 32) |
                    ((unsigned long long)(unsigned)(1023 - c) << 16) |
                    (unsigned long long)blist[bi];
                partial[((size_t)vt * T_STEPS + t) * BCAP + bi] = key;
            }
        }
    }
}

// ---------------------------------------------------------------------------
// k_gather: grid (32 bi-chunks, 16 t), block 256. Reads counts/partial across
// the kernel boundary (full visibility). Per valid bi: max-reduce the 16
// vt-keys (higher score wins; tie -> higher (1023-v) -> lower v, matching
// jnp.argmax), decode (b, v), copy the raw winning vector (bit-exact).
// ---------------------------------------------------------------------------
__global__ __launch_bounds__(256) void k_gather(const float* __restrict__ L,
                                                const int* __restrict__ counts,
                                                const unsigned long long* __restrict__ partial,
                                                float* __restrict__ out) {
    __shared__ int vArr[64];
    __shared__ int bArr[64];

    const int t  = blockIdx.y;
    const int cs = blockIdx.x * 64;
    const int n  = counts[t];
    if (cs >= n) return;

    const int tid = threadIdx.x;
    const int nb  = min(64, n - cs);
    if (tid < nb) {
        const int bi = cs + tid;
        unsigned long long best = partial[(size_t)t * BCAP + bi];   // vt=0
        #pragma unroll
        for (int q = 1; q < 16; ++q) {
            const unsigned long long k2 =
                partial[((size_t)q * T_STEPS + t) * BCAP + bi];
            if (k2 > best) best = k2;
        }
        vArr[tid] = 1023 - (int)((best >> 16) & 0xffffull);
        bArr[tid] = (int)(best & 0xffffull);
    }
    __syncthreads();

    const int l32 = tid & 31;
    for (int q = tid >> 5; q < nb; q += 8) {
        const int b = bArr[q], v = vArr[q];
        ((float4*)out)[b * 32 + l32] =
            ((const float4*)L)[(size_t)(t * V_VECS + v) * 32 + l32];
    }
}

extern "C" void kernel_launch(void* const* d_in, const int* in_sizes, int n_in,
                              void* d_out, int out_size, void* d_ws, size_t ws_size,
                              hipStream_t stream) {
    const float* X  = (const float*)d_in[0];   // (B, D, 1) f32
    const float* L  = (const float*)d_in[1];   // (T, V, D) f32
    const int* idx  = (const int*)d_in[2];     // (B,) int
    float* out      = (float*)d_out;           // (B, D) f32

    char* ws = (char*)d_ws;
    int* counts               = (int*)ws;                              // 64 B
    unsigned long long* part  = (unsigned long long*)(ws + 4096);      // 4 MiB

    hipLaunchKernelGGL(k_score,  dim3(16, 16, 4), dim3(256), 0, stream,
                       X, L, idx, part, counts);
    hipLaunchKernelGGL(k_gather, dim3(32, 16),    dim3(256), 0, stream,
                       L, counts, part, out);
}

// Round 12
// 28.016 us; speedup vs baseline: 1.1320x; 1.1320x over previous
//
#include <hip/hip_runtime.h>
#include <cstdint>

#define T_STEPS 16
#define V_VECS  1024
#define D_DIM   128
#define B_BATCH 2048
#define BCAP    2048          // per-t list capacity (bulletproof: n <= B)

// ---------------------------------------------------------------------------
// k_score: grid (16 vtiles, 16 t, 2 z), block 256 = 16(tv) x 16(tb).
// EXACT round-7 structure (z=2, stride-128 chunk loop, A+X in LDS,
// 2 blocks/CU) -- the best measured point (28.3us) -- with two isolated,
// strictly-better swaps:
//   (1) barrier-light phase 0: 8 idx loads issued back-to-back (vmcnt
//       pipelining), ONE barrier, uniform prefix from wcnt[8][4]
//       (r7 had 16 barriers + 8 serially-dependent loads);
//   (2) u16 blist (-4 KB LDS).
// z=4 grids measured ~3us WORSE (r10/r11): every extra block pays full
// phase-0 before exiting. Keep 512 blocks.
//
// Phase 2 chunk loop, FMA order, epilogue, packed keys are byte-identical
// to r7 => bit-identical scores. Cross-block visibility via the KERNEL
// BOUNDARY only (intra-kernel protocols failed rounds 4-6).
// ---------------------------------------------------------------------------
__global__ __launch_bounds__(256) void k_score(const float* __restrict__ X,
                                               const float* __restrict__ L,
                                               const int* __restrict__ idx,
                                               unsigned long long* __restrict__ partial,
                                               int* __restrict__ counts) {
    __shared__ __align__(16) float As[D_DIM][64];   // 32 KB
    __shared__ __align__(16) float Xs[D_DIM][64];   // 32 KB
    __shared__ float npart[4][64];                  // 1 KB
    __shared__ float invn_s[64];
    __shared__ unsigned short blist[BCAP];          // 4 KB
    __shared__ int wcnt[8][4];

    const int t    = blockIdx.y;
    const int vt   = blockIdx.x;
    const int v0   = vt * 64;
    const int z    = blockIdx.z;
    const int tid  = threadIdx.x;
    const int lane = tid & 63;
    const int w    = tid >> 6;

    // ---- phase 0: barrier-light bucketing ----
    bool mm[8]; int wpre[8];
    #pragma unroll
    for (int r = 0; r < 8; ++r) {
        const bool m = (idx[r * 256 + tid] == t);
        const unsigned long long bal = __ballot(m);
        mm[r]   = m;
        wpre[r] = __popcll(bal & ((1ull << lane) - 1ull));
        if (lane == 0) wcnt[r][w] = __popcll(bal);
    }
    __syncthreads();
    int run = 0;
    #pragma unroll
    for (int r = 0; r < 8; ++r) {
        int base = run;
        #pragma unroll
        for (int w2 = 0; w2 < 4; ++w2) {
            const int c = wcnt[r][w2];      // LDS broadcast (uniform)
            if (w2 < w) base += c;
            run += c;
        }
        if (mm[r]) blist[base + wpre[r]] = (unsigned short)(r * 256 + tid);
    }
    const int n = run;
    if (vt == 0 && z == 0 && tid == 0) counts[t] = n;   // before early return
    if (z * 64 >= n) return;             // uniform across blocks of t

    // ---- phase 1: stage A^T once (k-major) + fused inverse norms ----
    const float4* LA = (const float4*)(L + (size_t)(t * V_VECS + v0) * D_DIM);
    float ss = 0.f;
    #pragma unroll
    for (int p = 0; p < 8; ++p) {
        const int k4 = w + 4 * p;              // 0..31
        const float4 g = LA[lane * 32 + k4];
        As[4 * k4 + 0][lane] = g.x;
        As[4 * k4 + 1][lane] = g.y;
        As[4 * k4 + 2][lane] = g.z;
        As[4 * k4 + 3][lane] = g.w;
        ss += g.x * g.x + g.y * g.y + g.z * g.z + g.w * g.w;
    }
    npart[w][lane] = ss;
    __syncthreads();
    if (tid < 64) {
        const float s = npart[0][tid] + npart[1][tid] + npart[2][tid] + npart[3][tid];
        invn_s[tid] = rsqrtf(fmaxf(s, 1e-12f));
    }
    // invn_s visible to all after the barrier inside the chunk loop.

    const int tv = tid & 15;     // v-group: v = v0 + tv*4 + i
    const int tb = tid >> 4;     // b-group: b-slot = cs + tb*4 + j
    const float4* XA = (const float4*)X;

    // ---- phase 2: chunk loop (identical to round 7) ----
    for (int cs = z * 64; cs < n; cs += 128) {
        __syncthreads();         // prior Xs reads + npart/invn writes settled

        const int brow = cs + lane;
        const int bg = (brow < n) ? (int)blist[brow] : -1;
        const float4* xr = XA + (size_t)(bg < 0 ? 0 : bg) * 32;
        #pragma unroll
        for (int p = 0; p < 8; ++p) {
            const int k4 = w + 4 * p;
            float4 g = make_float4(0.f, 0.f, 0.f, 0.f);
            if (bg >= 0) g = xr[k4];
            Xs[4 * k4 + 0][lane] = g.x;
            Xs[4 * k4 + 1][lane] = g.y;
            Xs[4 * k4 + 2][lane] = g.z;
            Xs[4 * k4 + 3][lane] = g.w;
        }
        __syncthreads();

        float acc[4][4] = {};
        #pragma unroll 16
        for (int k = 0; k < D_DIM; ++k) {
            const float4 av = *(const float4*)&As[k][tv * 4];
            const float4 xb = *(const float4*)&Xs[k][tb * 4];
            const float a[4] = {av.x, av.y, av.z, av.w};
            const float x[4] = {xb.x, xb.y, xb.z, xb.w};
            #pragma unroll
            for (int i = 0; i < 4; ++i)
                #pragma unroll
                for (int j = 0; j < 4; ++j)
                    acc[i][j] += a[i] * x[j];
        }

        // ---- epilogue: argmax over v per b ----
        const float4 inv4 = *(const float4*)&invn_s[tv * 4];
        const float invp[4] = {inv4.x, inv4.y, inv4.z, inv4.w};

        #pragma unroll
        for (int j = 0; j < 4; ++j) {
            float s = acc[0][j] * invp[0];
            int   c = v0 + tv * 4;
            #pragma unroll
            for (int i = 1; i < 4; ++i) {
                const float si = acc[i][j] * invp[i];
                const int   ci = v0 + tv * 4 + i;
                if (si > s) { s = si; c = ci; }      // strict: lowest v wins tie
            }
            #pragma unroll
            for (int m = 8; m >= 1; m >>= 1) {       // reduce across tv lanes
                const float u  = __shfl_xor(s, m);
                const int   cu = __shfl_xor(c, m);
                if (u > s || (u == s && cu < c)) { s = u; c = cu; }
            }
            if (tv == 0) {
                const int bi = cs + tb * 4 + j;
                if (bi < n) {
                    unsigned int ub = __float_as_uint(s);
                    ub = (ub & 0x80000000u) ? ~ub : (ub | 0x80000000u);
                    const unsigned long long key =
                        ((unsigned long long)ub << 32) |
                        ((unsigned long long)(unsigned)(1023 - c) << 16) |
                        (unsigned long long)blist[bi];
                    partial[((size_t)vt * T_STEPS + t) * BCAP + bi] = key;
                }
            }
        }
    }
}

// ---------------------------------------------------------------------------
// k_gather: grid (32 bi-chunks, 16 t), block 256. Reads counts/partial across
// the kernel boundary (full visibility). Per valid bi: max-reduce the 16
// vt-keys (higher score wins; tie -> higher (1023-v) -> lower v, matching
// jnp.argmax), decode (b, v), copy the raw winning vector (bit-exact).
// ---------------------------------------------------------------------------
__global__ __launch_bounds__(256) void k_gather(const float* __restrict__ L,
                                                const int* __restrict__ counts,
                                                const unsigned long long* __restrict__ partial,
                                                float* __restrict__ out) {
    __shared__ int vArr[64];
    __shared__ int bArr[64];

    const int t  = blockIdx.y;
    const int cs = blockIdx.x * 64;
    const int n  = counts[t];
    if (cs >= n) return;

    const int tid = threadIdx.x;
    const int nb  = min(64, n - cs);
    if (tid < nb) {
        const int bi = cs + tid;
        unsigned long long best = partial[(size_t)t * BCAP + bi];   // vt=0
        #pragma unroll
        for (int q = 1; q < 16; ++q) {
            const unsigned long long k2 =
                partial[((size_t)q * T_STEPS + t) * BCAP + bi];
            if (k2 > best) best = k2;
        }
        vArr[tid] = 1023 - (int)((best >> 16) & 0xffffull);
        bArr[tid] = (int)(best & 0xffffull);
    }
    __syncthreads();

    const int l32 = tid & 31;
    for (int q = tid >> 5; q < nb; q += 8) {
        const int b = bArr[q], v = vArr[q];
        ((float4*)out)[b * 32 + l32] =
            ((const float4*)L)[(size_t)(t * V_VECS + v) * 32 + l32];
    }
}

extern "C" void kernel_launch(void* const* d_in, const int* in_sizes, int n_in,
                              void* d_out, int out_size, void* d_ws, size_t ws_size,
                              hipStream_t stream) {
    const float* X  = (const float*)d_in[0];   // (B, D, 1) f32
    const float* L  = (const float*)d_in[1];   // (T, V, D) f32
    const int* idx  = (const int*)d_in[2];     // (B,) int
    float* out      = (float*)d_out;           // (B, D) f32

    char* ws = (char*)d_ws;
    int* counts               = (int*)ws;                              // 64 B
    unsigned long long* part  = (unsigned long long*)(ws + 4096);      // 4 MiB

    hipLaunchKernelGGL(k_score,  dim3(16, 16, 2), dim3(256), 0, stream,
                       X, L, idx, part, counts);
    hipLaunchKernelGGL(k_gather, dim3(32, 16),    dim3(256), 0, stream,
                       L, counts, part, out);
}

// Round 13
// 25.633 us; speedup vs baseline: 1.2372x; 1.0930x over previous
//
#include <hip/hip_runtime.h>
#include <cstdint>

#define T_STEPS 16
#define V_VECS  1024
#define D_DIM   128
#define B_BATCH 2048
#define BCAP    2048          // per-t list capacity (bulletproof: n <= B)

// ---------------------------------------------------------------------------
// k_score: grid (16 vtiles, 16 t, 2 z), block 256 = 16(tv) x 16(tb).
// r12 base (28.0us) + load-balance fix:
//   - total chunk-units ~620 over 512 blocks; old static split made some CUs
//     run 4 serial chunk-units (two 2-chunk blocks). Now each z-block runs
//     its 64-b chunk plus HALF of the third chunk (32 b's, 4v x 2b tile):
//     max 1.5 units/block, max 3/CU. Safety loop (stride-128 from 192)
//     keeps any-n correctness.
//   - A-tile global loads hoisted ABOVE phase 0 (no dependency) -> latency
//     hidden under ballot work.
// Per-(v,b) k-accumulation order identical to r7/r12 => bit-identical
// scores. Cross-block visibility via the KERNEL BOUNDARY only.
// ---------------------------------------------------------------------------
__global__ __launch_bounds__(256) void k_score(const float* __restrict__ X,
                                               const float* __restrict__ L,
                                               const int* __restrict__ idx,
                                               unsigned long long* __restrict__ partial,
                                               int* __restrict__ counts) {
    __shared__ __align__(16) float As[D_DIM][64];   // 32 KB
    __shared__ __align__(16) float Xs[D_DIM][64];   // 32 KB
    __shared__ float npart[4][64];                  // 1 KB
    __shared__ float invn_s[64];
    __shared__ unsigned short blist[BCAP];          // 4 KB
    __shared__ int wcnt[8][4];

    const int t    = blockIdx.y;
    const int vt   = blockIdx.x;
    const int v0   = vt * 64;
    const int z    = blockIdx.z;
    const int tid  = threadIdx.x;
    const int lane = tid & 63;
    const int w    = tid >> 6;

    // ---- A-tile prefetch (independent of phase 0 -> issue first) ----
    const float4* LA = (const float4*)(L + (size_t)(t * V_VECS + v0) * D_DIM);
    float4 areg[8];
    #pragma unroll
    for (int p = 0; p < 8; ++p) areg[p] = LA[lane * 32 + (w + 4 * p)];

    // ---- phase 0: barrier-light bucketing ----
    bool mm[8]; int wpre[8];
    #pragma unroll
    for (int r = 0; r < 8; ++r) {
        const bool m = (idx[r * 256 + tid] == t);
        const unsigned long long bal = __ballot(m);
        mm[r]   = m;
        wpre[r] = __popcll(bal & ((1ull << lane) - 1ull));
        if (lane == 0) wcnt[r][w] = __popcll(bal);
    }
    __syncthreads();
    int run = 0;
    #pragma unroll
    for (int r = 0; r < 8; ++r) {
        int base = run;
        #pragma unroll
        for (int w2 = 0; w2 < 4; ++w2) {
            const int c = wcnt[r][w2];      // LDS broadcast (uniform)
            if (w2 < w) base += c;
            run += c;
        }
        if (mm[r]) blist[base + wpre[r]] = (unsigned short)(r * 256 + tid);
    }
    const int n = run;
    if (vt == 0 && z == 0 && tid == 0) counts[t] = n;   // before early return
    if (z * 64 >= n) return;             // uniform across blocks of t

    // ---- phase 1: write prefetched A^T (k-major) + fused inverse norms ----
    float ss = 0.f;
    #pragma unroll
    for (int p = 0; p < 8; ++p) {
        const int k4 = w + 4 * p;              // 0..31
        const float4 g = areg[p];
        As[4 * k4 + 0][lane] = g.x;
        As[4 * k4 + 1][lane] = g.y;
        As[4 * k4 + 2][lane] = g.z;
        As[4 * k4 + 3][lane] = g.w;
        ss += g.x * g.x + g.y * g.y + g.z * g.z + g.w * g.w;
    }
    npart[w][lane] = ss;
    __syncthreads();
    if (tid < 64) {
        const float s = npart[0][tid] + npart[1][tid] + npart[2][tid] + npart[3][tid];
        invn_s[tid] = rsqrtf(fmaxf(s, 1e-12f));
    }
    // invn_s visible after the barrier at the top of each chunk.

    const int tv = tid & 15;     // v-group: v = v0 + tv*4 + i
    const int tb = tid >> 4;     // b-group
    const float4* XA = (const float4*)X;

    // ---- phase 2a: full 64-b chunks: cs = z*64, then 192+z*64, 320+... ----
    int cs = z * 64;
    bool first = true;
    while (cs < n) {
        __syncthreads();         // prior Xs reads + npart/invn writes settled

        const int brow = cs + lane;
        const int bg = (brow < n) ? (int)blist[brow] : -1;
        const float4* xr = XA + (size_t)(bg < 0 ? 0 : bg) * 32;
        #pragma unroll
        for (int p = 0; p < 8; ++p) {
            const int k4 = w + 4 * p;
            float4 g = make_float4(0.f, 0.f, 0.f, 0.f);
            if (bg >= 0) g = xr[k4];
            Xs[4 * k4 + 0][lane] = g.x;
            Xs[4 * k4 + 1][lane] = g.y;
            Xs[4 * k4 + 2][lane] = g.z;
            Xs[4 * k4 + 3][lane] = g.w;
        }
        __syncthreads();

        float acc[4][4] = {};
        #pragma unroll 16
        for (int k = 0; k < D_DIM; ++k) {
            const float4 av = *(const float4*)&As[k][tv * 4];
            const float4 xb = *(const float4*)&Xs[k][tb * 4];
            const float a[4] = {av.x, av.y, av.z, av.w};
            const float x[4] = {xb.x, xb.y, xb.z, xb.w};
            #pragma unroll
            for (int i = 0; i < 4; ++i)
                #pragma unroll
                for (int j = 0; j < 4; ++j)
                    acc[i][j] += a[i] * x[j];
        }

        const float4 inv4 = *(const float4*)&invn_s[tv * 4];
        const float invp[4] = {inv4.x, inv4.y, inv4.z, inv4.w};

        #pragma unroll
        for (int j = 0; j < 4; ++j) {
            float s = acc[0][j] * invp[0];
            int   c = v0 + tv * 4;
            #pragma unroll
            for (int i = 1; i < 4; ++i) {
                const float si = acc[i][j] * invp[i];
                const int   ci = v0 + tv * 4 + i;
                if (si > s) { s = si; c = ci; }      // strict: lowest v wins tie
            }
            #pragma unroll
            for (int m = 8; m >= 1; m >>= 1) {       // reduce across tv lanes
                const float u  = __shfl_xor(s, m);
                const int   cu = __shfl_xor(c, m);
                if (u > s || (u == s && cu < c)) { s = u; c = cu; }
            }
            if (tv == 0) {
                const int bi = cs + tb * 4 + j;
                if (bi < n) {
                    unsigned int ub = __float_as_uint(s);
                    ub = (ub & 0x80000000u) ? ~ub : (ub | 0x80000000u);
                    const unsigned long long key =
                        ((unsigned long long)ub << 32) |
                        ((unsigned long long)(unsigned)(1023 - c) << 16) |
                        (unsigned long long)blist[bi];
                    partial[((size_t)vt * T_STEPS + t) * BCAP + bi] = key;
                }
            }
        }
        cs = first ? (192 + z * 64) : (cs + 128);
        first = false;
    }

    // ---- phase 2b: 32-b half chunk [128+z*32, 160+z*32) ----
    const int hs = 128 + z * 32;
    if (hs < n) {
        __syncthreads();         // prior Xs reads settled

        const int hrow = tid >> 3;           // 0..31
        const int hk8  = tid & 7;            // 0..7
        const int hb   = hs + hrow;
        const int hbg  = (hb < n) ? (int)blist[hb] : -1;
        const float4* hxr = XA + (size_t)(hbg < 0 ? 0 : hbg) * 32;
        #pragma unroll
        for (int p = 0; p < 4; ++p) {
            const int k4 = hk8 + 8 * p;      // 0..31
            float4 g = make_float4(0.f, 0.f, 0.f, 0.f);
            if (hbg >= 0) g = hxr[k4];
            Xs[4 * k4 + 0][hrow] = g.x;
            Xs[4 * k4 + 1][hrow] = g.y;
            Xs[4 * k4 + 2][hrow] = g.z;
            Xs[4 * k4 + 3][hrow] = g.w;
        }
        __syncthreads();

        const int tb2 = tid >> 4;            // 0..15, 2 cols each
        float hacc[4][2] = {};
        #pragma unroll 16
        for (int k = 0; k < D_DIM; ++k) {
            const float4 av = *(const float4*)&As[k][tv * 4];
            const float2 xb = *(const float2*)&Xs[k][tb2 * 2];
            const float a[4] = {av.x, av.y, av.z, av.w};
            const float x[2] = {xb.x, xb.y};
            #pragma unroll
            for (int i = 0; i < 4; ++i)
                #pragma unroll
                for (int j = 0; j < 2; ++j)
                    hacc[i][j] += a[i] * x[j];
        }

        const float4 inv4 = *(const float4*)&invn_s[tv * 4];
        const float invp[4] = {inv4.x, inv4.y, inv4.z, inv4.w};

        #pragma unroll
        for (int j = 0; j < 2; ++j) {
            float s = hacc[0][j] * invp[0];
            int   c = v0 + tv * 4;
            #pragma unroll
            for (int i = 1; i < 4; ++i) {
                const float si = hacc[i][j] * invp[i];
                const int   ci = v0 + tv * 4 + i;
                if (si > s) { s = si; c = ci; }      // strict: lowest v wins tie
            }
            #pragma unroll
            for (int m = 8; m >= 1; m >>= 1) {       // reduce across tv lanes
                const float u  = __shfl_xor(s, m);
                const int   cu = __shfl_xor(c, m);
                if (u > s || (u == s && cu < c)) { s = u; c = cu; }
            }
            if (tv == 0) {
                const int bi = hs + tb2 * 2 + j;
                if (bi < n) {
                    unsigned int ub = __float_as_uint(s);
                    ub = (ub & 0x80000000u) ? ~ub : (ub | 0x80000000u);
                    const unsigned long long key =
                        ((unsigned long long)ub << 32) |
                        ((unsigned long long)(unsigned)(1023 - c) << 16) |
                        (unsigned long long)blist[bi];
                    partial[((size_t)vt * T_STEPS + t) * BCAP + bi] = key;
                }
            }
        }
    }
}

// ---------------------------------------------------------------------------
// k_gather: grid (3 bi-chunks, 16 t) = 48 blocks + safety loop (stride 192).
// Reads counts/partial across the kernel boundary. Per valid bi: max-reduce
// the 16 vt-keys (ties -> lower v, matches jnp.argmax), decode (b, v), copy
// the raw winning vector (bit-exact).
// ---------------------------------------------------------------------------
__global__ __launch_bounds__(256) void k_gather(const float* __restrict__ L,
                                                const int* __restrict__ counts,
                                                const unsigned long long* __restrict__ partial,
                                                float* __restrict__ out) {
    __shared__ int vArr[64];
    __shared__ int bArr[64];

    const int t   = blockIdx.y;
    const int n   = counts[t];
    const int tid = threadIdx.x;
    const int l32 = tid & 31;

    for (int cs = blockIdx.x * 64; cs < n; cs += 192) {
        const int nb = min(64, n - cs);
        if (tid < nb) {
            const int bi = cs + tid;
            unsigned long long best = partial[(size_t)t * BCAP + bi];   // vt=0
            #pragma unroll
            for (int q = 1; q < 16; ++q) {
                const unsigned long long k2 =
                    partial[((size_t)q * T_STEPS + t) * BCAP + bi];
                if (k2 > best) best = k2;
            }
            vArr[tid] = 1023 - (int)((best >> 16) & 0xffffull);
            bArr[tid] = (int)(best & 0xffffull);
        }
        __syncthreads();
        for (int q = tid >> 5; q < nb; q += 8) {
            const int b = bArr[q], v = vArr[q];
            ((float4*)out)[b * 32 + l32] =
                ((const float4*)L)[(size_t)(t * V_VECS + v) * 32 + l32];
        }
        __syncthreads();
    }
}

extern "C" void kernel_launch(void* const* d_in, const int* in_sizes, int n_in,
                              void* d_out, int out_size, void* d_ws, size_t ws_size,
                              hipStream_t stream) {
    const float* X  = (const float*)d_in[0];   // (B, D, 1) f32
    const float* L  = (const float*)d_in[1];   // (T, V, D) f32
    const int* idx  = (const int*)d_in[2];     // (B,) int
    float* out      = (float*)d_out;           // (B, D) f32

    char* ws = (char*)d_ws;
    int* counts               = (int*)ws;                              // 64 B
    unsigned long long* part  = (unsigned long long*)(ws + 4096);      // 4 MiB

    hipLaunchKernelGGL(k_score,  dim3(16, 16, 2), dim3(256), 0, stream,
                       X, L, idx, part, counts);
    hipLaunchKernelGGL(k_gather, dim3(3, 16),     dim3(256), 0, stream,
                       L, counts, part, out);
}